// Round 1
// 2159.810 us; speedup vs baseline: 1.4617x; 1.4617x over previous
//
#include <hip/hip_runtime.h>

// ============================================================================
// DecoderGenerator: 2-layer LSTM decoder + additive attention + big vocab
// projection + NLL, fully fused on-device.
//
//   1. prep_kernel     : bf16-cast weights/enc, gather embeddings, transpose
//                        enc, init h-state buffers, zero barrier flags.
//   2. a0_kernel       : A0 = xs @ W_ih0^T + b  (hoisted layer-0 input GEMM)
//   3. lstm_kernel     : persistent 32-WG x 512-thread kernel, 129 ticks.
//                        ROUND 6: fence-free tick exchange. All cross-WG h
//                        traffic is relaxed agent-scope atomics (LLC-coherent,
//                        cache-bypassing), so no buffer_wbl2/buffer_inv per
//                        tick and no per-poll ACQUIRE invalidations. A0
//                        prefetch issued AFTER publish so it overlaps the
//                        poll. Staging trimmed to exactly 16KB(+16KB).
//   4. phpe_kernel     : ph = Hall@Wh^T ; pe = enc@We^T + attn_b
//   5. logits_kernel   : logits[t,b,l] = sum_k v_w[k] tanh(ph+pe)
//   6. att_kernel      : softmax over b (axis=1 of (T,B,L) — per reference!)
//   7. weighted_kernel : weighted = att @ enc  (per-batch GEMM) -> G[:,512:]
//   8. fc_kernel       : fused GEMM (G @ fc_W^T) + per-row (max,sumexp)
//   9. tgt_kernel      : target logits z_y per row
//  10. finalize_kernel : logsumexp merge + masked-mean NLL -> d_out[0]
// ============================================================================

#define DI __device__ __forceinline__

typedef __attribute__((ext_vector_type(8))) short short8;
typedef __attribute__((ext_vector_type(4))) float floatx4;

#define TSEQ   128
#define VOCAB  32000
#define GDIM   2048   // 4*H
#define NROW   2048   // B*T
#define KFC    1024   // 2*H
#define HPAD   520    // LDS row stride for h staging (512 + 8 pad)

// ---------------- small helpers ----------------
DI float bf2f(unsigned short u) {
    union { unsigned u; float f; } x; x.u = ((unsigned)u) << 16; return x.f;
}
DI unsigned short f2bf(float f) {   // RNE float -> bf16
    unsigned u = __float_as_uint(f);
    unsigned r = (u + 0x7FFF + ((u >> 16) & 1)) >> 16;
    return (unsigned short)r;
}
DI short8 ld8(const unsigned short* p) { return *(const short8*)p; }
DI floatx4 mfma16(short8 a, short8 b, floatx4 c) {
    return __builtin_amdgcn_mfma_f32_16x16x32_bf16(a, b, c, 0, 0, 0);
}
DI float sigm(float x) { return __builtin_amdgcn_rcpf(1.f + __expf(-x)); }
DI float tanh_f(float x) {
    float xc = fminf(8.f, fmaxf(-8.f, x));
    float e  = __expf(2.f * xc);
    return (e - 1.f) * __builtin_amdgcn_rcpf(e + 1.f);
}

// fallback path: make the failure visible instead of faulting
__global__ void zero_out_kernel(float* out, int n) {
    int i = blockIdx.x * 64 + threadIdx.x;
    if (i < n) out[i] = 0.f;
}

// ============================================================================
// 1. prep kernel : segmented grid-stride over all conversion jobs
//    total work = 4*1048576 + 2*262144 + 3*1048576 + 16384 = 7,880,704
//    grid = 30,784 blocks x 256.
// ============================================================================
__global__ void prep_kernel(const int* X, const float* enc, const float* emb,
                            const float* Wih0, const float* Whh0,
                            const float* Wih1, const float* Whh1,
                            const float* attnW, const float* h0,
                            unsigned short* wih0b, unsigned short* whh0b,
                            unsigned short* wih1b, unsigned short* whh1b,
                            unsigned short* whb, unsigned short* web,
                            unsigned short* encb, unsigned short* enctb,
                            unsigned short* xsb,
                            unsigned short* h0buf, unsigned short* h1buf,
                            int* ctrl) {
    if (blockIdx.x == 0) {              // zero all 1024 flag ints
#pragma unroll
        for (int j = 0; j < 4; ++j) ctrl[threadIdx.x + 256 * j] = 0;
    }
    long i = (long)blockIdx.x * 256 + threadIdx.x;
    const long NW = 1048576;
    const long NA = 262144;            // 512x512 half of attn_W
    if (i < NW) { wih0b[i] = f2bf(Wih0[i]); return; } i -= NW;
    if (i < NW) { whh0b[i] = f2bf(Whh0[i]); return; } i -= NW;
    if (i < NW) { wih1b[i] = f2bf(Wih1[i]); return; } i -= NW;
    if (i < NW) { whh1b[i] = f2bf(Whh1[i]); return; } i -= NW;
    if (i < NA) { long k = i >> 9, h = i & 511; whb[i] = f2bf(attnW[k * 1024 + h]);       return; } i -= NA;
    if (i < NA) { long k = i >> 9, h = i & 511; web[i] = f2bf(attnW[k * 1024 + 512 + h]); return; } i -= NA;
    if (i < NW) { encb[i] = f2bf(enc[i]); return; } i -= NW;
    if (i < NW) {  // enc_t[b][h][l] = enc[b][l][h]
        long b = i >> 16, r = i & 65535, h = r >> 7, l = r & 127;
        enctb[i] = f2bf(enc[(b * 128 + l) * 512 + h]); return;
    } i -= NW;
    if (i < NW) {  // xs[t*16+b][e] = emb[X[b][t]][e]
        long m = i >> 9, e = i & 511, t = m >> 4, b = m & 15;
        int xi = X[b * 129 + t];
        xi = (xi < 0) ? 0 : ((xi >= VOCAB) ? VOCAB - 1 : xi);   // defensive
        xsb[i] = f2bf(emb[(long)xi * 512 + e]); return;
    } i -= NW;
    if (i < 16384) {  // h inits into parity-1 buffers
        long layer = i >> 13, r = i & 8191;
        unsigned short v = f2bf(h0[layer * 8192 + r]);
        if (layer == 0) h0buf[8192 + r] = v; else h1buf[8192 + r] = v;
    }
}

// ============================================================================
// shared 64x64 MFMA tile: C[m0..+63][n0..+63] += A(m,k) * B(n,k)^T
// ============================================================================
DI void gemm64_acc(const unsigned short* A, const unsigned short* Bw,
                   int m0, int n0, int lda, int ldb, int nkb, floatx4 acc[4]) {
    int tid = threadIdx.x;
    int wv = tid >> 6, ln = tid & 63;
    int colL = ln & 15, koff = (ln >> 4) * 8;
    const unsigned short* ar  = A  + (size_t)(m0 + wv * 16 + colL) * lda + koff;
    const unsigned short* br0 = Bw + (size_t)(n0 +  0 + colL) * ldb + koff;
    const unsigned short* br1 = Bw + (size_t)(n0 + 16 + colL) * ldb + koff;
    const unsigned short* br2 = Bw + (size_t)(n0 + 32 + colL) * ldb + koff;
    const unsigned short* br3 = Bw + (size_t)(n0 + 48 + colL) * ldb + koff;
    for (int kb = 0; kb < nkb; ++kb) {
        short8 af = ld8(ar + kb * 32);
        acc[0] = mfma16(af, ld8(br0 + kb * 32), acc[0]);
        acc[1] = mfma16(af, ld8(br1 + kb * 32), acc[1]);
        acc[2] = mfma16(af, ld8(br2 + kb * 32), acc[2]);
        acc[3] = mfma16(af, ld8(br3 + kb * 32), acc[3]);
    }
}

// 2. A0 = xs @ W_ih0^T + (b_ih0 + b_hh0), stored bf16 (bias folded)
__global__ void a0_kernel(const unsigned short* xs, const unsigned short* wih0b,
                          const float* bih0, const float* bhh0, unsigned short* A0b) {
    floatx4 acc[4] = {{0,0,0,0},{0,0,0,0},{0,0,0,0},{0,0,0,0}};
    int m0 = blockIdx.x * 64, n0 = blockIdx.y * 64;
    gemm64_acc(xs, wih0b, m0, n0, 512, 512, 16, acc);
    int tid = threadIdx.x, wv = tid >> 6, ln = tid & 63, colL = ln & 15, q = ln >> 4;
    int mrow = m0 + wv * 16;
#pragma unroll
    for (int nt = 0; nt < 4; ++nt) {
        int col = n0 + nt * 16 + colL;
        float bb = bih0[col] + bhh0[col];
#pragma unroll
        for (int r = 0; r < 4; ++r)
            A0b[(size_t)(mrow + q * 4 + r) * GDIM + col] = f2bf(acc[nt][r] + bb);
    }
}

// ============================================================================
// 3. persistent LSTM kernel.  32 WGs x 512 threads.
//    Per WG: threads 0..255 = layer0 slice (units u0..u0+15),
//            threads 256..511 = layer1 slice (same units).
//    tick t: L0 half computes h0[t] (t<128), L1 half computes h1[t-1] (t>=1).
//
//    ROUND 6 exchange protocol (fence-free):
//      - h0buf/h1buf stores and loads are RELAXED agent-scope atomics. These
//        carry LLC-scope cache bits (same path as device-scope atomicAdd,
//        which is HW-coherent across XCDs), so neither buffer_wbl2 on the
//        producer nor buffer_inv on the consumer is needed.
//      - publish: __syncthreads() (hipcc drains vmcnt(0) before s_barrier =>
//        all h-stores acknowledged at LLC), then thread 0 stores the per-WG
//        monotonic tick flag (relaxed).
//      - A0 prefetch for t+1 is issued AFTER publish, BEFORE polling, so the
//        LLC round trip hides under the barrier wait (previously it was
//        drained by the fence *before* publish, lengthening the tick).
//      - wait: lanes 0..31 of wave 0 poll the 32 flags with RELAXED loads
//        (no per-iteration L1/L2 invalidate), then __syncthreads().
// ============================================================================
__global__ __launch_bounds__(512, 1)
void lstm_kernel(const unsigned short* A0b,
                 const unsigned short* whh0b, const unsigned short* wih1b,
                 const unsigned short* whh1b,
                 const float* bih1, const float* bhh1, const float* c0in,
                 unsigned short* h0buf, unsigned short* h1buf,
                 unsigned short* Hall, unsigned short* Gmat, int* flags) {
    __shared__ unsigned short hsh0[16 * HPAD];   // h0[t-1], shared by both halves
    __shared__ unsigned short hsh1[16 * HPAD];   // h1[t-2], L1 half only
    __shared__ float gbuf[2][4][16][16];         // [half][gate][batch][unit]
    int wg = blockIdx.x;            // 0..31
    int tid = threadIdx.x;          // 0..511
    int half = tid >> 8;            // 0 = L0, 1 = L1
    int lt   = tid & 255;
    int wv = lt >> 6, ln = lt & 63;
    int u0 = wg * 16;
    int n0 = wv * 512 + u0;         // gate column base (wave-of-half = gate)
    int colL = ln & 15, q = ln >> 4, koff = q * 8;
    int eb = lt >> 4, eu = lt & 15; // elementwise mapping within half
    float c = c0in[half * 8192 + eb * 512 + u0 + eu];
    float bias1 = (half == 1) ? (bih1[n0 + colL] + bhh1[n0 + colL]) : 0.f;

    // ---- one-time: weight slices into registers (128 VGPRs) ----
    short8 wA[16], wB[16];
    if (half == 0) {
        const unsigned short* wr0 = whh0b + (size_t)(n0 + colL) * 512 + koff;
#pragma unroll
        for (int kb = 0; kb < 16; ++kb) wA[kb] = ld8(wr0 + kb * 32);
#pragma unroll
        for (int kb = 0; kb < 16; ++kb) wB[kb] = wA[kb];   // unused, keep defined
    } else {
        const unsigned short* wr1 = wih1b + (size_t)(n0 + colL) * 512 + koff;
        const unsigned short* wr2 = whh1b + (size_t)(n0 + colL) * 512 + koff;
#pragma unroll
        for (int kb = 0; kb < 16; ++kb) wA[kb] = ld8(wr1 + kb * 32);
#pragma unroll
        for (int kb = 0; kb < 16; ++kb) wB[kb] = ld8(wr2 + kb * 32);
    }

    // A0 prefetch for tick 0 (L0 half)
    floatx4 a0pre = {0, 0, 0, 0};
    if (half == 0) {
        const unsigned short* a0r = A0b + (size_t)0 * GDIM + n0 + colL;
        a0pre[0] = bf2f(a0r[(q * 4 + 0) * GDIM]);
        a0pre[1] = bf2f(a0r[(q * 4 + 1) * GDIM]);
        a0pre[2] = bf2f(a0r[(q * 4 + 2) * GDIM]);
        a0pre[3] = bf2f(a0r[(q * 4 + 3) * GDIM]);
    }

    // staging geometry: thread tid covers ushorts [tid*16, tid*16+16) x2 rows?
    // flat = tid*16 over [16][512]: row = tid>>5, col = (tid&31)*16. 32B/thread.
    int srow = tid >> 5;
    int scol = (tid & 31) << 4;
    unsigned long long* d0 = (unsigned long long*)&hsh0[srow * HPAD + scol];
    unsigned long long* d1 = (unsigned long long*)&hsh1[srow * HPAD + scol];

#pragma unroll 1
    for (int t = 0; t <= TSEQ; ++t) {
        bool actL0 = (t < TSEQ);
        bool actL1 = (t >= 1);
        // ---- stage h vectors LLC -> LDS (relaxed agent atomics, 16KB each) ----
        {
            const unsigned long long* s0 =
                (const unsigned long long*)(h0buf + ((t - 1) & 1) * 8192) + (size_t)tid * 4;
            unsigned long long v0 = __hip_atomic_load(s0 + 0, __ATOMIC_RELAXED, __HIP_MEMORY_SCOPE_AGENT);
            unsigned long long v1 = __hip_atomic_load(s0 + 1, __ATOMIC_RELAXED, __HIP_MEMORY_SCOPE_AGENT);
            unsigned long long v2 = __hip_atomic_load(s0 + 2, __ATOMIC_RELAXED, __HIP_MEMORY_SCOPE_AGENT);
            unsigned long long v3 = __hip_atomic_load(s0 + 3, __ATOMIC_RELAXED, __HIP_MEMORY_SCOPE_AGENT);
            if (actL1) {
                const unsigned long long* s1 =
                    (const unsigned long long*)(h1buf + ((t - 2) & 1) * 8192) + (size_t)tid * 4;
                unsigned long long w0 = __hip_atomic_load(s1 + 0, __ATOMIC_RELAXED, __HIP_MEMORY_SCOPE_AGENT);
                unsigned long long w1 = __hip_atomic_load(s1 + 1, __ATOMIC_RELAXED, __HIP_MEMORY_SCOPE_AGENT);
                unsigned long long w2 = __hip_atomic_load(s1 + 2, __ATOMIC_RELAXED, __HIP_MEMORY_SCOPE_AGENT);
                unsigned long long w3 = __hip_atomic_load(s1 + 3, __ATOMIC_RELAXED, __HIP_MEMORY_SCOPE_AGENT);
                d0[0] = v0; d0[1] = v1; d0[2] = v2; d0[3] = v3;
                d1[0] = w0; d1[1] = w1; d1[2] = w2; d1[3] = w3;
            } else {
                d0[0] = v0; d0[1] = v1; d0[2] = v2; d0[3] = v3;
            }
        }
        __syncthreads();
        // ---- MFMA: LDS fragments x register weights ----
        bool act = half ? actL1 : actL0;
        if (act) {
            floatx4 acc;
            const unsigned short* hl0 = hsh0 + colL * HPAD + koff;
            if (half == 0) {
                acc = a0pre;
#pragma unroll
                for (int kb = 0; kb < 16; ++kb)
                    acc = mfma16(ld8(hl0 + kb * 32), wA[kb], acc);
            } else {
                acc[0] = bias1; acc[1] = bias1; acc[2] = bias1; acc[3] = bias1;
                const unsigned short* hl1 = hsh1 + colL * HPAD + koff;
#pragma unroll
                for (int kb = 0; kb < 16; ++kb)
                    acc = mfma16(ld8(hl0 + kb * 32), wA[kb], acc);
#pragma unroll
                for (int kb = 0; kb < 16; ++kb)
                    acc = mfma16(ld8(hl1 + kb * 32), wB[kb], acc);
            }
            // D layout: row = batch = q*4+r, col = unit = colL
            gbuf[half][wv][q * 4 + 0][colL] = acc[0];
            gbuf[half][wv][q * 4 + 1][colL] = acc[1];
            gbuf[half][wv][q * 4 + 2][colL] = acc[2];
            gbuf[half][wv][q * 4 + 3][colL] = acc[3];
        }
        __syncthreads();
        if (act) {
            float gi = gbuf[half][0][eb][eu], gf = gbuf[half][1][eb][eu];
            float gg = gbuf[half][2][eb][eu], go = gbuf[half][3][eb][eu];
            float c2 = sigm(gf) * c + sigm(gi) * tanh_f(gg);
            float h2 = sigm(go) * tanh_f(c2);
            c = c2;
            // pack lane pairs (eu, eu+1) -> one uint, store via relaxed agent
            // atomics (straight to LLC; no cache flush needed at publish).
            unsigned hb = (unsigned)f2bf(h2);
            unsigned up = __shfl_down(hb, 1, 64);
            unsigned packed = hb | (up << 16);
            if ((eu & 1) == 0) {
                if (half == 0) {
                    __hip_atomic_store(
                        (unsigned*)(h0buf + (t & 1) * 8192 + eb * 512 + u0 + eu),
                        packed, __ATOMIC_RELAXED, __HIP_MEMORY_SCOPE_AGENT);
                } else {
                    int s = t - 1;
                    __hip_atomic_store(
                        (unsigned*)(h1buf + (s & 1) * 8192 + eb * 512 + u0 + eu),
                        packed, __ATOMIC_RELAXED, __HIP_MEMORY_SCOPE_AGENT);
                    // Hall/Gmat: consumed by later kernels only; normal cached
                    // stores (flushed at kernel end).
                    *(unsigned*)&Hall[(size_t)(s * 16 + eb) * 512 + u0 + eu] = packed;
                    *(unsigned*)&Gmat[(size_t)(eb * 128 + s) * KFC + u0 + eu] = packed;
                }
            }
        }
        if (t < TSEQ) {
            // publish: barrier drains all waves' vmcnt (hipcc emits
            // s_waitcnt vmcnt(0) before s_barrier), so every h-store is
            // complete at the LLC before the flag moves.
            __syncthreads();
            if (tid == 0)
                __hip_atomic_store(flags + wg * 32, t + 1,
                                   __ATOMIC_RELAXED, __HIP_MEMORY_SCOPE_AGENT);
            // prefetch next tick's A0 now — overlaps the poll window
            if (half == 0 && t + 1 < TSEQ) {
                const unsigned short* a0r = A0b + (size_t)((t + 1) * 16) * GDIM + n0 + colL;
                a0pre[0] = bf2f(a0r[(q * 4 + 0) * GDIM]);
                a0pre[1] = bf2f(a0r[(q * 4 + 1) * GDIM]);
                a0pre[2] = bf2f(a0r[(q * 4 + 2) * GDIM]);
                a0pre[3] = bf2f(a0r[(q * 4 + 3) * GDIM]);
            }
            // wait: relaxed polls (no buffer_inv per iteration)
            if (tid < 32) {
                int guard = 0;
                while (__hip_atomic_load(flags + tid * 32, __ATOMIC_RELAXED,
                                         __HIP_MEMORY_SCOPE_AGENT) < t + 1) {
                    __builtin_amdgcn_s_sleep(1);
                    if (++guard > (1 << 22)) break;   // fail loud, not hung
                }
            }
            __syncthreads();
        }
    }
}

// 4. ph = Hall @ Wh^T ; pe = enc @ We^T + attn_b   (z selects)
__global__ void phpe_kernel(const unsigned short* Hall, const unsigned short* encb,
                            const unsigned short* whb, const unsigned short* web,
                            const float* attnb, float* ph, float* pe) {
    bool ispe = (blockIdx.z != 0);
    const unsigned short* A  = ispe ? encb : Hall;
    const unsigned short* Bw = ispe ? web  : whb;
    float* out = ispe ? pe : ph;
    floatx4 acc[4] = {{0,0,0,0},{0,0,0,0},{0,0,0,0},{0,0,0,0}};
    int m0 = blockIdx.x * 64, n0 = blockIdx.y * 64;
    gemm64_acc(A, Bw, m0, n0, 512, 512, 16, acc);
    int tid = threadIdx.x, wv = tid >> 6, ln = tid & 63, colL = ln & 15, q = ln >> 4;
    int mrow = m0 + wv * 16;
#pragma unroll
    for (int nt = 0; nt < 4; ++nt) {
        int col = n0 + nt * 16 + colL;
        float bb = ispe ? attnb[col] : 0.f;
#pragma unroll
        for (int r = 0; r < 4; ++r)
            out[(size_t)(mrow + q * 4 + r) * 512 + col] = acc[nt][r] + bb;
    }
}

// 5. logits[t][l][b] = sum_k v_w[k] * tanh(ph[t*16+b][k] + pe[b*128+l][k])
__global__ void logits_kernel(const float* ph, const float* pe, const float* vw,
                              float* logits) {
    int m = blockIdx.x;             // t*16+b
    int t = m >> 4, b = m & 15;
    int tid = threadIdx.x, wv = tid >> 6, ln = tid & 63;
    const float* phr = ph + (size_t)m * 512 + ln * 8;
    floatx4 ph0 = *(const floatx4*)phr;
    floatx4 ph1 = *(const floatx4*)(phr + 4);
    const float* vwr = vw + ln * 8;
    floatx4 vw0 = *(const floatx4*)vwr;
    floatx4 vw1 = *(const floatx4*)(vwr + 4);
    for (int li = 0; li < 32; ++li) {
        int ll = wv * 32 + li;
        const float* per = pe + (size_t)(b * 128 + ll) * 512 + ln * 8;
        floatx4 p0 = *(const floatx4*)per;
        floatx4 p1 = *(const floatx4*)(per + 4);
        float s = 0.f;
#pragma unroll
        for (int j = 0; j < 4; ++j) s += vw0[j] * tanh_f(ph0[j] + p0[j]);
#pragma unroll
        for (int j = 0; j < 4; ++j) s += vw1[j] * tanh_f(ph1[j] + p1[j]);
#pragma unroll
        for (int off = 32; off; off >>= 1) s += __shfl_xor(s, off, 64);
        if (ln == 0) logits[((size_t)t * 128 + ll) * 16 + b] = s;
    }
}

// 6. softmax over b (axis=1 of (T,B,L)) -> att_bf16[b][t][l]
__global__ void att_kernel(const float* logits, unsigned short* attb) {
    int t = blockIdx.x, l = threadIdx.x;     // 128 threads
    const float* p = logits + ((size_t)t * 128 + l) * 16;
    float x[16], mx = -1e30f;
#pragma unroll
    for (int j = 0; j < 16; ++j) { x[j] = p[j]; mx = fmaxf(mx, x[j]); }
    float s = 0.f;
#pragma unroll
    for (int j = 0; j < 16; ++j) { x[j] = __expf(x[j] - mx); s += x[j]; }
    float inv = __builtin_amdgcn_rcpf(s);
#pragma unroll
    for (int j = 0; j < 16; ++j)
        attb[((size_t)j * 128 + t) * 128 + l] = f2bf(x[j] * inv);
}

// 7. weighted[b][t][h] = att[b] @ enc[b]  ->  G[b*128+t][512+h]
__global__ void weighted_kernel(const unsigned short* attb, const unsigned short* enctb,
                                unsigned short* Gmat) {
    int b = blockIdx.z;
    floatx4 acc[4] = {{0,0,0,0},{0,0,0,0},{0,0,0,0},{0,0,0,0}};
    int m0 = blockIdx.x * 64, n0 = blockIdx.y * 64;
    gemm64_acc(attb + (size_t)b * 128 * 128, enctb + (size_t)b * 512 * 128,
               m0, n0, 128, 128, 4, acc);
    int tid = threadIdx.x, wv = tid >> 6, ln = tid & 63, colL = ln & 15, q = ln >> 4;
    int mrow = m0 + wv * 16;
#pragma unroll
    for (int nt = 0; nt < 4; ++nt) {
        int col = n0 + nt * 16 + colL;
#pragma unroll
        for (int r = 0; r < 4; ++r)
            Gmat[(size_t)(b * 128 + mrow + q * 4 + r) * KFC + 512 + col] = f2bf(acc[nt][r]);
    }
}

// ============================================================================
// 8. fc GEMM + fused per-row (max, sumexp) partials.
// ============================================================================
__global__ __launch_bounds__(512, 2)
void fc_kernel(const unsigned short* G, const float* fcW, const float* fcb,
               float2* partials) {
    int wgn = blockIdx.x;
    int tid = threadIdx.x, wv = tid >> 6, ln = tid & 63;
    int colL = ln & 15, q = ln >> 4, koff = q * 8;
    int n0 = wgn * 128 + wv * 16;
    const float* wrow = fcW + (size_t)(n0 + colL) * KFC + koff;
    short8 Bf[32];
#pragma unroll
    for (int kb = 0; kb < 32; ++kb) {
        short8 v;
#pragma unroll
        for (int j = 0; j < 8; ++j) v[j] = (short)f2bf(wrow[kb * 32 + j]);
        Bf[kb] = v;
    }
    float cb = fcb[n0 + colL];
    __shared__ float2 pbuf[128][8];

    for (int mb = 0; mb < 16; ++mb) {
        floatx4 acc[8];
#pragma unroll
        for (int mt = 0; mt < 8; ++mt) acc[mt] = (floatx4){0,0,0,0};
        const unsigned short* gbase =
            G + (size_t)(mb * 128 + colL) * KFC + koff;
#pragma unroll
        for (int kb = 0; kb < 32; ++kb) {
#pragma unroll
            for (int mt = 0; mt < 8; ++mt) {
                short8 af = ld8(gbase + (size_t)mt * 16 * KFC + kb * 32);
                acc[mt] = mfma16(af, Bf[kb], acc[mt]);
            }
        }
        __syncthreads();   // pbuf reuse guard vs previous mb's merge
#pragma unroll
        for (int mt = 0; mt < 8; ++mt) {
#pragma unroll
            for (int r = 0; r < 4; ++r) {
                float v = acc[mt][r] + cb;
                float M = v;
#pragma unroll
                for (int off = 1; off < 16; off <<= 1) M = fmaxf(M, __shfl_xor(M, off, 64));
                float e = __expf(v - M);
#pragma unroll
                for (int off = 1; off < 16; off <<= 1) e += __shfl_xor(e, off, 64);
                if (colL == 0) pbuf[mt * 16 + q * 4 + r][wv] = make_float2(M, e);
            }
        }
        __syncthreads();
        if (tid < 128) {   // merge 8 waves -> one partial per (row, WG)
            float2 a = pbuf[tid][0];
            float M = a.x, S = a.y;
#pragma unroll
            for (int w = 1; w < 8; ++w) {
                float2 p = pbuf[tid][w];
                float nm = fmaxf(M, p.x);
                S = S * __expf(M - nm) + p.y * __expf(p.x - nm);
                M = nm;
            }
            partials[(size_t)(mb * 128 + tid) * 250 + wgn] = make_float2(M, S);
        }
    }
}

// 9. target logit per row: z_y = G[r] . fc_W[y] + fc_b[y]
__global__ void tgt_kernel(const unsigned short* G, const float* fcW, const float* fcb,
                           const int* X, float* tgt) {
    int r = blockIdx.x * 4 + (threadIdx.x >> 6);
    int ln = threadIdx.x & 63;
    int b = r >> 7, t = r & 127;
    int y = X[b * 129 + t + 1];
    y = (y < 0) ? 0 : ((y >= VOCAB) ? VOCAB - 1 : y);   // defensive
    const unsigned short* g = G + (size_t)r * KFC;
    const float* w = fcW + (size_t)y * KFC;
    float s = 0.f;
    for (int j = ln; j < KFC; j += 64) s += bf2f(g[j]) * w[j];
#pragma unroll
    for (int off = 32; off; off >>= 1) s += __shfl_xor(s, off, 64);
    if (ln == 0) tgt[r] = s + fcb[y];
}

// 10. merge partials -> logsumexp -> masked mean NLL
__global__ void finalize_kernel(const float2* partials, const float* tgt,
                                const int* X, float* out) {
    int tid = threadIdx.x;
    float vs = 0.f, vc = 0.f;
    for (int r = tid; r < NROW; r += 256) {
        const float2* p = partials + (size_t)r * 250;
        float M = p[0].x, S = p[0].y;
        for (int i = 1; i < 250; ++i) {
            float2 qq = p[i];
            float nm = fmaxf(M, qq.x);
            S = S * __expf(M - nm) + qq.y * __expf(qq.x - nm);
            M = nm;
        }
        float lse = M + __logf(S);
        int b = r >> 7, t = r & 127;
        int y = X[b * 129 + t + 1];
        if (y != 0) { vs += lse - tgt[r]; vc += 1.f; }
    }
    __shared__ float sv[256], sc[256];
    sv[tid] = vs; sc[tid] = vc;
    __syncthreads();
    for (int s = 128; s; s >>= 1) {
        if (tid < s) { sv[tid] += sv[tid + s]; sc[tid] += sc[tid + s]; }
        __syncthreads();
    }
    if (tid == 0) out[0] = sv[0] / sc[0];
}

// ============================================================================
// launcher
// ============================================================================
extern "C" void kernel_launch(void* const* d_in, const int* in_sizes, int n_in,
                              void* d_out, int out_size, void* d_ws, size_t ws_size,
                              hipStream_t stream) {
    const int*   X     = (const int*)d_in[0];
    const float* enc   = (const float*)d_in[2];
    const float* emb   = (const float*)d_in[3];
    const float* Wih0  = (const float*)d_in[4];
    const float* Whh0  = (const float*)d_in[5];
    const float* bih0  = (const float*)d_in[6];
    const float* bhh0  = (const float*)d_in[7];
    const float* Wih1  = (const float*)d_in[8];
    const float* Whh1  = (const float*)d_in[9];
    const float* bih1  = (const float*)d_in[10];
    const float* bhh1  = (const float*)d_in[11];
    const float* attnW = (const float*)d_in[12];
    const float* attnb = (const float*)d_in[13];
    const float* vw    = (const float*)d_in[14];
    const float* fcW   = (const float*)d_in[15];
    const float* fcb   = (const float*)d_in[16];
    const float* h0    = (const float*)d_in[17];
    const float* c0    = (const float*)d_in[18];

    char* ws = (char*)d_ws;
    size_t off = 0;
    auto take = [&](size_t bytes) { char* p = ws + off; off += (bytes + 255) & ~(size_t)255; return p; };
    int*            ctrl    = (int*)           take(4096);
    unsigned short* wih0b   = (unsigned short*)take(2097152);
    unsigned short* whh0b   = (unsigned short*)take(2097152);
    unsigned short* wih1b   = (unsigned short*)take(2097152);
    unsigned short* whh1b   = (unsigned short*)take(2097152);
    unsigned short* whb     = (unsigned short*)take(524288);
    unsigned short* web     = (unsigned short*)take(524288);
    unsigned short* encb    = (unsigned short*)take(2097152);
    unsigned short* enctb   = (unsigned short*)take(2097152);
    unsigned short* xsb     = (unsigned short*)take(2097152);
    unsigned short* h0buf   = (unsigned short*)take(32768);
    unsigned short* h1buf   = (unsigned short*)take(32768);
    unsigned short* A0b     = (unsigned short*)take(8388608);
    unsigned short* hallb   = (unsigned short*)take(2097152);
    unsigned short* gmat    = (unsigned short*)take(4194304);
    float*          ph      = (float*)         take(4194304);
    float*          pe      = (float*)         take(4194304);
    float*          logitsb = (float*)         take(1048576);
    unsigned short* attb    = (unsigned short*)take(524288);
    float2*         parts   = (float2*)        take(4096000);
    float*          tgt     = (float*)         take(8192);
    size_t need = off;
    (void)in_sizes; (void)n_in;

    if (ws_size < need) {
        // Not enough scratch: fail visibly (absmax error) instead of faulting.
        hipLaunchKernelGGL(zero_out_kernel, dim3((out_size + 63) / 64), dim3(64),
                           0, stream, (float*)d_out, out_size);
        return;
    }

    hipLaunchKernelGGL(prep_kernel, dim3(30784), dim3(256), 0, stream,
                       X, enc, emb, Wih0, Whh0, Wih1, Whh1, attnW, h0,
                       wih0b, whh0b, wih1b, whh1b, whb, web, encb, enctb,
                       xsb, h0buf, h1buf, ctrl);
    hipLaunchKernelGGL(a0_kernel, dim3(32, 32), dim3(256), 0, stream,
                       xsb, wih0b, bih0, bhh0, A0b);
    hipLaunchKernelGGL(lstm_kernel, dim3(32), dim3(512), 0, stream,
                       A0b, whh0b, wih1b, whh1b, bih1, bhh1, c0,
                       h0buf, h1buf, hallb, gmat, ctrl);
    hipLaunchKernelGGL(phpe_kernel, dim3(32, 8, 2), dim3(256), 0, stream,
                       hallb, encb, whb, web, attnb, ph, pe);
    hipLaunchKernelGGL(logits_kernel, dim3(2048), dim3(256), 0, stream,
                       ph, pe, vw, logitsb);
    hipLaunchKernelGGL(att_kernel, dim3(128), dim3(128), 0, stream,
                       logitsb, attb);
    hipLaunchKernelGGL(weighted_kernel, dim3(2, 8, 16), dim3(256), 0, stream,
                       attb, enctb, gmat);
    hipLaunchKernelGGL(fc_kernel, dim3(250), dim3(512), 0, stream,
                       gmat, fcW, fcb, parts);
    hipLaunchKernelGGL(tgt_kernel, dim3(512), dim3(256), 0, stream,
                       gmat, fcW, fcb, X, tgt);
    hipLaunchKernelGGL(finalize_kernel, dim3(1), dim3(256), 0, stream,
                       parts, tgt, X, (float*)d_out);
}

// Round 2
// 1309.118 us; speedup vs baseline: 2.4116x; 1.6498x over previous
//
#include <hip/hip_runtime.h>

// ============================================================================
// DecoderGenerator: 2-layer LSTM decoder + additive attention + big vocab
// projection + NLL, fully fused on-device.
//
//   1. prep_kernel     : bf16-cast weights/enc/fcW, gather embeddings,
//                        transpose enc, init h-state buffers, zero flags.
//   2. a0_kernel       : A0 = xs @ W_ih0^T + b  (hoisted layer-0 input GEMM)
//   3. lstm_kernel     : persistent 32-WG x 512-thread kernel, 129 ticks.
//                        (ROUND 6 fence-free relaxed-atomic exchange.)
//   4. phpe_kernel     : ph = Hall@Wh^T ; pe = enc@We^T + attn_b
//   5. logits_kernel   : logits[t,b,l] = sum_k v_w[k] tanh(ph+pe)
//   6. att_kernel      : softmax over b (axis=1 of (T,B,L) — per reference!)
//   7. weighted_kernel : weighted = att @ enc  (per-batch GEMM) -> G[:,512:]
//   8. fc_kernel       : ROUND 7: m97-structure 128x128xBK64 tiled GEMM
//                        (global_load_lds staging, 4x4 register fragments, no
//                        spills) + fused per-row (max,sumexp) partials.
//   9. tgt_kernel      : target logits z_y per row
//  10. finalize_kernel : logsumexp merge + masked-mean NLL -> d_out[0]
// ============================================================================

#define DI __device__ __forceinline__

typedef __attribute__((ext_vector_type(8))) short short8;
typedef __attribute__((ext_vector_type(4))) float floatx4;

#define TSEQ   128
#define VOCAB  32000
#define GDIM   2048   // 4*H
#define NROW   2048   // B*T
#define KFC    1024   // 2*H
#define HPAD   520    // LDS row stride for h staging (512 + 8 pad)

// ---------------- small helpers ----------------
DI float bf2f(unsigned short u) {
    union { unsigned u; float f; } x; x.u = ((unsigned)u) << 16; return x.f;
}
DI unsigned short f2bf(float f) {   // RNE float -> bf16
    unsigned u = __float_as_uint(f);
    unsigned r = (u + 0x7FFF + ((u >> 16) & 1)) >> 16;
    return (unsigned short)r;
}
DI short8 ld8(const unsigned short* p) { return *(const short8*)p; }
DI floatx4 mfma16(short8 a, short8 b, floatx4 c) {
    return __builtin_amdgcn_mfma_f32_16x16x32_bf16(a, b, c, 0, 0, 0);
}
DI float sigm(float x) { return __builtin_amdgcn_rcpf(1.f + __expf(-x)); }
DI float tanh_f(float x) {
    float xc = fminf(8.f, fmaxf(-8.f, x));
    float e  = __expf(2.f * xc);
    return (e - 1.f) * __builtin_amdgcn_rcpf(e + 1.f);
}

// async global -> LDS, 16B per lane. LDS dest must be wave-uniform base;
// lane l writes base + l*16. Global src is per-lane.
#define GLD16(gsrc, ldst)                                                     \
    __builtin_amdgcn_global_load_lds(                                         \
        (const __attribute__((address_space(1))) unsigned int*)(gsrc),        \
        (__attribute__((address_space(3))) unsigned int*)(ldst), 16, 0, 0)

// fallback path: make the failure visible instead of faulting
__global__ void zero_out_kernel(float* out, int n) {
    int i = blockIdx.x * 64 + threadIdx.x;
    if (i < n) out[i] = 0.f;
}

// ============================================================================
// 1. prep kernel : segmented grid-stride over all conversion jobs
//    total work = 7,880,704 + 8,192,000 (fcW float4 groups) = 16,072,704
//    grid = 62,784 blocks x 256.
// ============================================================================
__global__ void prep_kernel(const int* X, const float* enc, const float* emb,
                            const float* Wih0, const float* Whh0,
                            const float* Wih1, const float* Whh1,
                            const float* attnW, const float* h0,
                            const float* fcW,
                            unsigned short* wih0b, unsigned short* whh0b,
                            unsigned short* wih1b, unsigned short* whh1b,
                            unsigned short* whb, unsigned short* web,
                            unsigned short* encb, unsigned short* enctb,
                            unsigned short* xsb,
                            unsigned short* h0buf, unsigned short* h1buf,
                            unsigned short* fcWb,
                            int* ctrl) {
    if (blockIdx.x == 0) {              // zero all 1024 flag ints
#pragma unroll
        for (int j = 0; j < 4; ++j) ctrl[threadIdx.x + 256 * j] = 0;
    }
    long i = (long)blockIdx.x * 256 + threadIdx.x;
    const long NW = 1048576;
    const long NA = 262144;            // 512x512 half of attn_W
    if (i < NW) { wih0b[i] = f2bf(Wih0[i]); return; } i -= NW;
    if (i < NW) { whh0b[i] = f2bf(Whh0[i]); return; } i -= NW;
    if (i < NW) { wih1b[i] = f2bf(Wih1[i]); return; } i -= NW;
    if (i < NW) { whh1b[i] = f2bf(Whh1[i]); return; } i -= NW;
    if (i < NA) { long k = i >> 9, h = i & 511; whb[i] = f2bf(attnW[k * 1024 + h]);       return; } i -= NA;
    if (i < NA) { long k = i >> 9, h = i & 511; web[i] = f2bf(attnW[k * 1024 + 512 + h]); return; } i -= NA;
    if (i < NW) { encb[i] = f2bf(enc[i]); return; } i -= NW;
    if (i < NW) {  // enc_t[b][h][l] = enc[b][l][h]
        long b = i >> 16, r = i & 65535, h = r >> 7, l = r & 127;
        enctb[i] = f2bf(enc[(b * 128 + l) * 512 + h]); return;
    } i -= NW;
    if (i < NW) {  // xs[t*16+b][e] = emb[X[b][t]][e]
        long m = i >> 9, e = i & 511, t = m >> 4, b = m & 15;
        int xi = X[b * 129 + t];
        xi = (xi < 0) ? 0 : ((xi >= VOCAB) ? VOCAB - 1 : xi);   // defensive
        xsb[i] = f2bf(emb[(long)xi * 512 + e]); return;
    } i -= NW;
    if (i < 16384) {  // h inits into parity-1 buffers
        long layer = i >> 13, r = i & 8191;
        unsigned short v = f2bf(h0[layer * 8192 + r]);
        if (layer == 0) h0buf[8192 + r] = v; else h1buf[8192 + r] = v;
        return;
    } i -= 16384;
    if (i < 8192000) {  // fcW f32 -> bf16, 4 elements per thread
        float4 v = ((const float4*)fcW)[i];
        ushort4 o;
        o.x = f2bf(v.x); o.y = f2bf(v.y); o.z = f2bf(v.z); o.w = f2bf(v.w);
        ((ushort4*)fcWb)[i] = o;
    }
}

// ============================================================================
// shared 64x64 MFMA tile: C[m0..+63][n0..+63] += A(m,k) * B(n,k)^T
// ============================================================================
DI void gemm64_acc(const unsigned short* A, const unsigned short* Bw,
                   int m0, int n0, int lda, int ldb, int nkb, floatx4 acc[4]) {
    int tid = threadIdx.x;
    int wv = tid >> 6, ln = tid & 63;
    int colL = ln & 15, koff = (ln >> 4) * 8;
    const unsigned short* ar  = A  + (size_t)(m0 + wv * 16 + colL) * lda + koff;
    const unsigned short* br0 = Bw + (size_t)(n0 +  0 + colL) * ldb + koff;
    const unsigned short* br1 = Bw + (size_t)(n0 + 16 + colL) * ldb + koff;
    const unsigned short* br2 = Bw + (size_t)(n0 + 32 + colL) * ldb + koff;
    const unsigned short* br3 = Bw + (size_t)(n0 + 48 + colL) * ldb + koff;
    for (int kb = 0; kb < nkb; ++kb) {
        short8 af = ld8(ar + kb * 32);
        acc[0] = mfma16(af, ld8(br0 + kb * 32), acc[0]);
        acc[1] = mfma16(af, ld8(br1 + kb * 32), acc[1]);
        acc[2] = mfma16(af, ld8(br2 + kb * 32), acc[2]);
        acc[3] = mfma16(af, ld8(br3 + kb * 32), acc[3]);
    }
}

// 2. A0 = xs @ W_ih0^T + (b_ih0 + b_hh0), stored bf16 (bias folded)
__global__ void a0_kernel(const unsigned short* xs, const unsigned short* wih0b,
                          const float* bih0, const float* bhh0, unsigned short* A0b) {
    floatx4 acc[4] = {{0,0,0,0},{0,0,0,0},{0,0,0,0},{0,0,0,0}};
    int m0 = blockIdx.x * 64, n0 = blockIdx.y * 64;
    gemm64_acc(xs, wih0b, m0, n0, 512, 512, 16, acc);
    int tid = threadIdx.x, wv = tid >> 6, ln = tid & 63, colL = ln & 15, q = ln >> 4;
    int mrow = m0 + wv * 16;
#pragma unroll
    for (int nt = 0; nt < 4; ++nt) {
        int col = n0 + nt * 16 + colL;
        float bb = bih0[col] + bhh0[col];
#pragma unroll
        for (int r = 0; r < 4; ++r)
            A0b[(size_t)(mrow + q * 4 + r) * GDIM + col] = f2bf(acc[nt][r] + bb);
    }
}

// ============================================================================
// 3. persistent LSTM kernel.  32 WGs x 512 threads. (unchanged, round 6)
// ============================================================================
__global__ __launch_bounds__(512, 1)
void lstm_kernel(const unsigned short* A0b,
                 const unsigned short* whh0b, const unsigned short* wih1b,
                 const unsigned short* whh1b,
                 const float* bih1, const float* bhh1, const float* c0in,
                 unsigned short* h0buf, unsigned short* h1buf,
                 unsigned short* Hall, unsigned short* Gmat, int* flags) {
    __shared__ unsigned short hsh0[16 * HPAD];   // h0[t-1], shared by both halves
    __shared__ unsigned short hsh1[16 * HPAD];   // h1[t-2], L1 half only
    __shared__ float gbuf[2][4][16][16];         // [half][gate][batch][unit]
    int wg = blockIdx.x;            // 0..31
    int tid = threadIdx.x;          // 0..511
    int half = tid >> 8;            // 0 = L0, 1 = L1
    int lt   = tid & 255;
    int wv = lt >> 6, ln = lt & 63;
    int u0 = wg * 16;
    int n0 = wv * 512 + u0;         // gate column base (wave-of-half = gate)
    int colL = ln & 15, q = ln >> 4, koff = q * 8;
    int eb = lt >> 4, eu = lt & 15; // elementwise mapping within half
    float c = c0in[half * 8192 + eb * 512 + u0 + eu];
    float bias1 = (half == 1) ? (bih1[n0 + colL] + bhh1[n0 + colL]) : 0.f;

    // ---- one-time: weight slices into registers (128 VGPRs) ----
    short8 wA[16], wB[16];
    if (half == 0) {
        const unsigned short* wr0 = whh0b + (size_t)(n0 + colL) * 512 + koff;
#pragma unroll
        for (int kb = 0; kb < 16; ++kb) wA[kb] = ld8(wr0 + kb * 32);
#pragma unroll
        for (int kb = 0; kb < 16; ++kb) wB[kb] = wA[kb];   // unused, keep defined
    } else {
        const unsigned short* wr1 = wih1b + (size_t)(n0 + colL) * 512 + koff;
        const unsigned short* wr2 = whh1b + (size_t)(n0 + colL) * 512 + koff;
#pragma unroll
        for (int kb = 0; kb < 16; ++kb) wA[kb] = ld8(wr1 + kb * 32);
#pragma unroll
        for (int kb = 0; kb < 16; ++kb) wB[kb] = ld8(wr2 + kb * 32);
    }

    // A0 prefetch for tick 0 (L0 half)
    floatx4 a0pre = {0, 0, 0, 0};
    if (half == 0) {
        const unsigned short* a0r = A0b + (size_t)0 * GDIM + n0 + colL;
        a0pre[0] = bf2f(a0r[(q * 4 + 0) * GDIM]);
        a0pre[1] = bf2f(a0r[(q * 4 + 1) * GDIM]);
        a0pre[2] = bf2f(a0r[(q * 4 + 2) * GDIM]);
        a0pre[3] = bf2f(a0r[(q * 4 + 3) * GDIM]);
    }

    // staging geometry: flat = tid*16 over [16][512]: row = tid>>5,
    // col = (tid&31)*16. 32B/thread.
    int srow = tid >> 5;
    int scol = (tid & 31) << 4;
    unsigned long long* d0 = (unsigned long long*)&hsh0[srow * HPAD + scol];
    unsigned long long* d1 = (unsigned long long*)&hsh1[srow * HPAD + scol];

#pragma unroll 1
    for (int t = 0; t <= TSEQ; ++t) {
        bool actL0 = (t < TSEQ);
        bool actL1 = (t >= 1);
        // ---- stage h vectors LLC -> LDS (relaxed agent atomics, 16KB each) ----
        {
            const unsigned long long* s0 =
                (const unsigned long long*)(h0buf + ((t - 1) & 1) * 8192) + (size_t)tid * 4;
            unsigned long long v0 = __hip_atomic_load(s0 + 0, __ATOMIC_RELAXED, __HIP_MEMORY_SCOPE_AGENT);
            unsigned long long v1 = __hip_atomic_load(s0 + 1, __ATOMIC_RELAXED, __HIP_MEMORY_SCOPE_AGENT);
            unsigned long long v2 = __hip_atomic_load(s0 + 2, __ATOMIC_RELAXED, __HIP_MEMORY_SCOPE_AGENT);
            unsigned long long v3 = __hip_atomic_load(s0 + 3, __ATOMIC_RELAXED, __HIP_MEMORY_SCOPE_AGENT);
            if (actL1) {
                const unsigned long long* s1 =
                    (const unsigned long long*)(h1buf + ((t - 2) & 1) * 8192) + (size_t)tid * 4;
                unsigned long long w0 = __hip_atomic_load(s1 + 0, __ATOMIC_RELAXED, __HIP_MEMORY_SCOPE_AGENT);
                unsigned long long w1 = __hip_atomic_load(s1 + 1, __ATOMIC_RELAXED, __HIP_MEMORY_SCOPE_AGENT);
                unsigned long long w2 = __hip_atomic_load(s1 + 2, __ATOMIC_RELAXED, __HIP_MEMORY_SCOPE_AGENT);
                unsigned long long w3 = __hip_atomic_load(s1 + 3, __ATOMIC_RELAXED, __HIP_MEMORY_SCOPE_AGENT);
                d0[0] = v0; d0[1] = v1; d0[2] = v2; d0[3] = v3;
                d1[0] = w0; d1[1] = w1; d1[2] = w2; d1[3] = w3;
            } else {
                d0[0] = v0; d0[1] = v1; d0[2] = v2; d0[3] = v3;
            }
        }
        __syncthreads();
        // ---- MFMA: LDS fragments x register weights ----
        bool act = half ? actL1 : actL0;
        if (act) {
            floatx4 acc;
            const unsigned short* hl0 = hsh0 + colL * HPAD + koff;
            if (half == 0) {
                acc = a0pre;
#pragma unroll
                for (int kb = 0; kb < 16; ++kb)
                    acc = mfma16(ld8(hl0 + kb * 32), wA[kb], acc);
            } else {
                acc[0] = bias1; acc[1] = bias1; acc[2] = bias1; acc[3] = bias1;
                const unsigned short* hl1 = hsh1 + colL * HPAD + koff;
#pragma unroll
                for (int kb = 0; kb < 16; ++kb)
                    acc = mfma16(ld8(hl0 + kb * 32), wA[kb], acc);
#pragma unroll
                for (int kb = 0; kb < 16; ++kb)
                    acc = mfma16(ld8(hl1 + kb * 32), wB[kb], acc);
            }
            // D layout: row = batch = q*4+r, col = unit = colL
            gbuf[half][wv][q * 4 + 0][colL] = acc[0];
            gbuf[half][wv][q * 4 + 1][colL] = acc[1];
            gbuf[half][wv][q * 4 + 2][colL] = acc[2];
            gbuf[half][wv][q * 4 + 3][colL] = acc[3];
        }
        __syncthreads();
        if (act) {
            float gi = gbuf[half][0][eb][eu], gf = gbuf[half][1][eb][eu];
            float gg = gbuf[half][2][eb][eu], go = gbuf[half][3][eb][eu];
            float c2 = sigm(gf) * c + sigm(gi) * tanh_f(gg);
            float h2 = sigm(go) * tanh_f(c2);
            c = c2;
            unsigned hb = (unsigned)f2bf(h2);
            unsigned up = __shfl_down(hb, 1, 64);
            unsigned packed = hb | (up << 16);
            if ((eu & 1) == 0) {
                if (half == 0) {
                    __hip_atomic_store(
                        (unsigned*)(h0buf + (t & 1) * 8192 + eb * 512 + u0 + eu),
                        packed, __ATOMIC_RELAXED, __HIP_MEMORY_SCOPE_AGENT);
                } else {
                    int s = t - 1;
                    __hip_atomic_store(
                        (unsigned*)(h1buf + (s & 1) * 8192 + eb * 512 + u0 + eu),
                        packed, __ATOMIC_RELAXED, __HIP_MEMORY_SCOPE_AGENT);
                    *(unsigned*)&Hall[(size_t)(s * 16 + eb) * 512 + u0 + eu] = packed;
                    *(unsigned*)&Gmat[(size_t)(eb * 128 + s) * KFC + u0 + eu] = packed;
                }
            }
        }
        if (t < TSEQ) {
            __syncthreads();
            if (tid == 0)
                __hip_atomic_store(flags + wg * 32, t + 1,
                                   __ATOMIC_RELAXED, __HIP_MEMORY_SCOPE_AGENT);
            if (half == 0 && t + 1 < TSEQ) {
                const unsigned short* a0r = A0b + (size_t)((t + 1) * 16) * GDIM + n0 + colL;
                a0pre[0] = bf2f(a0r[(q * 4 + 0) * GDIM]);
                a0pre[1] = bf2f(a0r[(q * 4 + 1) * GDIM]);
                a0pre[2] = bf2f(a0r[(q * 4 + 2) * GDIM]);
                a0pre[3] = bf2f(a0r[(q * 4 + 3) * GDIM]);
            }
            if (tid < 32) {
                int guard = 0;
                while (__hip_atomic_load(flags + tid * 32, __ATOMIC_RELAXED,
                                         __HIP_MEMORY_SCOPE_AGENT) < t + 1) {
                    __builtin_amdgcn_s_sleep(1);
                    if (++guard > (1 << 22)) break;   // fail loud, not hung
                }
            }
            __syncthreads();
        }
    }
}

// 4. ph = Hall @ Wh^T ; pe = enc @ We^T + attn_b   (z selects)
__global__ void phpe_kernel(const unsigned short* Hall, const unsigned short* encb,
                            const unsigned short* whb, const unsigned short* web,
                            const float* attnb, float* ph, float* pe) {
    bool ispe = (blockIdx.z != 0);
    const unsigned short* A  = ispe ? encb : Hall;
    const unsigned short* Bw = ispe ? web  : whb;
    float* out = ispe ? pe : ph;
    floatx4 acc[4] = {{0,0,0,0},{0,0,0,0},{0,0,0,0},{0,0,0,0}};
    int m0 = blockIdx.x * 64, n0 = blockIdx.y * 64;
    gemm64_acc(A, Bw, m0, n0, 512, 512, 16, acc);
    int tid = threadIdx.x, wv = tid >> 6, ln = tid & 63, colL = ln & 15, q = ln >> 4;
    int mrow = m0 + wv * 16;
#pragma unroll
    for (int nt = 0; nt < 4; ++nt) {
        int col = n0 + nt * 16 + colL;
        float bb = ispe ? attnb[col] : 0.f;
#pragma unroll
        for (int r = 0; r < 4; ++r)
            out[(size_t)(mrow + q * 4 + r) * 512 + col] = acc[nt][r] + bb;
    }
}

// 5. logits[t][l][b] = sum_k v_w[k] * tanh(ph[t*16+b][k] + pe[b*128+l][k])
__global__ void logits_kernel(const float* ph, const float* pe, const float* vw,
                              float* logits) {
    int m = blockIdx.x;             // t*16+b
    int t = m >> 4, b = m & 15;
    int tid = threadIdx.x, wv = tid >> 6, ln = tid & 63;
    const float* phr = ph + (size_t)m * 512 + ln * 8;
    floatx4 ph0 = *(const floatx4*)phr;
    floatx4 ph1 = *(const floatx4*)(phr + 4);
    const float* vwr = vw + ln * 8;
    floatx4 vw0 = *(const floatx4*)vwr;
    floatx4 vw1 = *(const floatx4*)(vwr + 4);
    for (int li = 0; li < 32; ++li) {
        int ll = wv * 32 + li;
        const float* per = pe + (size_t)(b * 128 + ll) * 512 + ln * 8;
        floatx4 p0 = *(const floatx4*)per;
        floatx4 p1 = *(const floatx4*)(per + 4);
        float s = 0.f;
#pragma unroll
        for (int j = 0; j < 4; ++j) s += vw0[j] * tanh_f(ph0[j] + p0[j]);
#pragma unroll
        for (int j = 0; j < 4; ++j) s += vw1[j] * tanh_f(ph1[j] + p1[j]);
#pragma unroll
        for (int off = 32; off; off >>= 1) s += __shfl_xor(s, off, 64);
        if (ln == 0) logits[((size_t)t * 128 + ll) * 16 + b] = s;
    }
}

// 6. softmax over b (axis=1 of (T,B,L)) -> att_bf16[b][t][l]
__global__ void att_kernel(const float* logits, unsigned short* attb) {
    int t = blockIdx.x, l = threadIdx.x;     // 128 threads
    const float* p = logits + ((size_t)t * 128 + l) * 16;
    float x[16], mx = -1e30f;
#pragma unroll
    for (int j = 0; j < 16; ++j) { x[j] = p[j]; mx = fmaxf(mx, x[j]); }
    float s = 0.f;
#pragma unroll
    for (int j = 0; j < 16; ++j) { x[j] = __expf(x[j] - mx); s += x[j]; }
    float inv = __builtin_amdgcn_rcpf(s);
#pragma unroll
    for (int j = 0; j < 16; ++j)
        attb[((size_t)j * 128 + t) * 128 + l] = f2bf(x[j] * inv);
}

// 7. weighted[b][t][h] = att[b] @ enc[b]  ->  G[b*128+t][512+h]
__global__ void weighted_kernel(const unsigned short* attb, const unsigned short* enctb,
                                unsigned short* Gmat) {
    int b = blockIdx.z;
    floatx4 acc[4] = {{0,0,0,0},{0,0,0,0},{0,0,0,0},{0,0,0,0}};
    int m0 = blockIdx.x * 64, n0 = blockIdx.y * 64;
    gemm64_acc(attb + (size_t)b * 128 * 128, enctb + (size_t)b * 512 * 128,
               m0, n0, 128, 128, 4, acc);
    int tid = threadIdx.x, wv = tid >> 6, ln = tid & 63, colL = ln & 15, q = ln >> 4;
    int mrow = m0 + wv * 16;
#pragma unroll
    for (int nt = 0; nt < 4; ++nt) {
        int col = n0 + nt * 16 + colL;
#pragma unroll
        for (int r = 0; r < 4; ++r)
            Gmat[(size_t)(b * 128 + mrow + q * 4 + r) * KFC + 512 + col] = f2bf(acc[nt][r]);
    }
}

// ============================================================================
// 8. fc GEMM (m97-structure) + fused per-row (max, sumexp) partials.
//    Grid (250 N-tiles, 16 M-tiles) x 256 threads (4 waves).
//    WG computes C[m_base..+128][n_base..+128]; wave (wr,wc) owns 64x64.
//    K-loop: 16 tiles of BK=64 staged A+B via global_load_lds (16B/lane),
//    2-barrier structure, 2 k-steps of 8 ds_read_b128 + 16 MFMA per tile.
//    acc[4][4] register-resident (~120 VGPR, no spill).
// ============================================================================
__global__ __launch_bounds__(256)
void fc_kernel(const unsigned short* G, const unsigned short* fcWb,
               const float* fcb, float2* partials) {
    __shared__ __align__(16) unsigned short lA[128 * 64];
    __shared__ __align__(16) unsigned short lB[128 * 64];
    __shared__ float2 pbuf[128][2];
    int nwg = blockIdx.x;            // 0..249
    int mwg = blockIdx.y;            // 0..15
    int n_base = nwg * 128, m_base = mwg * 128;
    int tid = threadIdx.x, wv = tid >> 6, l = tid & 63;
    int wr = wv >> 1, wc = wv & 1;
    int colL = l & 15, q16 = l >> 4, koff = q16 * 8;
    int srow = l >> 3, scol = (l & 7) * 8;     // staging sub-pattern per chunk

    floatx4 acc[4][4];
#pragma unroll
    for (int i = 0; i < 4; ++i)
#pragma unroll
        for (int j = 0; j < 4; ++j) acc[i][j] = (floatx4){0, 0, 0, 0};

    const unsigned short* gA = G    + (size_t)m_base * KFC;
    const unsigned short* gB = fcWb + (size_t)n_base * KFC;

    for (int kt = 0; kt < 16; ++kt) {
        if (kt) __syncthreads();     // previous tile's reads done before overwrite
        int k0 = kt * 64;
        // stage: 16 chunks of 1KB each (8 rows x 128B); wave wv does chunks
        // wv*4..wv*4+3 for both A and B. LDS dest is wave-uniform.
#pragma unroll
        for (int j = 0; j < 4; ++j) {
            int c = wv * 4 + j;
            const unsigned short* ga = gA + (size_t)(c * 8 + srow) * KFC + k0 + scol;
            const unsigned short* gb = gB + (size_t)(c * 8 + srow) * KFC + k0 + scol;
            GLD16(ga, lA + c * 512);
            GLD16(gb, lB + c * 512);
        }
        __syncthreads();             // barrier drains vmcnt -> tiles resident
#pragma unroll
        for (int ks = 0; ks < 2; ++ks) {
            const unsigned short* ap = lA + (wr * 64 + colL) * 64 + ks * 32 + koff;
            const unsigned short* bp = lB + (wc * 64 + colL) * 64 + ks * 32 + koff;
            short8 aF[4], bF[4];
#pragma unroll
            for (int ma = 0; ma < 4; ++ma) aF[ma] = ld8(ap + ma * 16 * 64);
#pragma unroll
            for (int nb = 0; nb < 4; ++nb) bF[nb] = ld8(bp + nb * 16 * 64);
#pragma unroll
            for (int ma = 0; ma < 4; ++ma)
#pragma unroll
                for (int nb = 0; nb < 4; ++nb)
                    acc[ma][nb] = mfma16(aF[ma], bF[nb], acc[ma][nb]);
        }
    }

    // ---- epilogue: per-row (max, sumexp) over this WG's 128 cols ----
    float cb[4];
#pragma unroll
    for (int nb = 0; nb < 4; ++nb)
        cb[nb] = fcb[n_base + wc * 64 + nb * 16 + colL];

#pragma unroll
    for (int ma = 0; ma < 4; ++ma) {
#pragma unroll
        for (int r = 0; r < 4; ++r) {
            // lane holds row = wr*64 + ma*16 + q16*4 + r, cols {wc*64+nb*16+colL}
            float v0 = acc[ma][0][r] + cb[0];
            float v1 = acc[ma][1][r] + cb[1];
            float v2 = acc[ma][2][r] + cb[2];
            float v3 = acc[ma][3][r] + cb[3];
            float M = fmaxf(fmaxf(v0, v1), fmaxf(v2, v3));
#pragma unroll
            for (int off = 1; off < 16; off <<= 1) M = fmaxf(M, __shfl_xor(M, off, 64));
            float e = __expf(v0 - M) + __expf(v1 - M) + __expf(v2 - M) + __expf(v3 - M);
#pragma unroll
            for (int off = 1; off < 16; off <<= 1) e += __shfl_xor(e, off, 64);
            if (colL == 0)
                pbuf[wr * 64 + ma * 16 + q16 * 4 + r][wc] = make_float2(M, e);
        }
    }
    __syncthreads();
    if (tid < 128) {    // merge the two col-halves, write global partial
        float2 a = pbuf[tid][0], b = pbuf[tid][1];
        float M = fmaxf(a.x, b.x);
        float S = a.y * __expf(a.x - M) + b.y * __expf(b.x - M);
        partials[(size_t)(m_base + tid) * 250 + nwg] = make_float2(M, S);
    }
}

// 9. target logit per row: z_y = G[r] . fc_W[y] + fc_b[y]
__global__ void tgt_kernel(const unsigned short* G, const float* fcW, const float* fcb,
                           const int* X, float* tgt) {
    int r = blockIdx.x * 4 + (threadIdx.x >> 6);
    int ln = threadIdx.x & 63;
    int b = r >> 7, t = r & 127;
    int y = X[b * 129 + t + 1];
    y = (y < 0) ? 0 : ((y >= VOCAB) ? VOCAB - 1 : y);   // defensive
    const unsigned short* g = G + (size_t)r * KFC;
    const float* w = fcW + (size_t)y * KFC;
    float s = 0.f;
    for (int j = ln; j < KFC; j += 64) s += bf2f(g[j]) * w[j];
#pragma unroll
    for (int off = 32; off; off >>= 1) s += __shfl_xor(s, off, 64);
    if (ln == 0) tgt[r] = s + fcb[y];
}

// 10. merge partials -> logsumexp -> masked mean NLL
__global__ void finalize_kernel(const float2* partials, const float* tgt,
                                const int* X, float* out) {
    int tid = threadIdx.x;
    float vs = 0.f, vc = 0.f;
    for (int r = tid; r < NROW; r += 256) {
        const float2* p = partials + (size_t)r * 250;
        float M = p[0].x, S = p[0].y;
        for (int i = 1; i < 250; ++i) {
            float2 qq = p[i];
            float nm = fmaxf(M, qq.x);
            S = S * __expf(M - nm) + qq.y * __expf(qq.x - nm);
            M = nm;
        }
        float lse = M + __logf(S);
        int b = r >> 7, t = r & 127;
        int y = X[b * 129 + t + 1];
        if (y != 0) { vs += lse - tgt[r]; vc += 1.f; }
    }
    __shared__ float sv[256], sc[256];
    sv[tid] = vs; sc[tid] = vc;
    __syncthreads();
    for (int s = 128; s; s >>= 1) {
        if (tid < s) { sv[tid] += sv[tid + s]; sc[tid] += sc[tid + s]; }
        __syncthreads();
    }
    if (tid == 0) out[0] = sv[0] / sc[0];
}

// ============================================================================
// launcher
// ============================================================================
extern "C" void kernel_launch(void* const* d_in, const int* in_sizes, int n_in,
                              void* d_out, int out_size, void* d_ws, size_t ws_size,
                              hipStream_t stream) {
    const int*   X     = (const int*)d_in[0];
    const float* enc   = (const float*)d_in[2];
    const float* emb   = (const float*)d_in[3];
    const float* Wih0  = (const float*)d_in[4];
    const float* Whh0  = (const float*)d_in[5];
    const float* bih0  = (const float*)d_in[6];
    const float* bhh0  = (const float*)d_in[7];
    const float* Wih1  = (const float*)d_in[8];
    const float* Whh1  = (const float*)d_in[9];
    const float* bih1  = (const float*)d_in[10];
    const float* bhh1  = (const float*)d_in[11];
    const float* attnW = (const float*)d_in[12];
    const float* attnb = (const float*)d_in[13];
    const float* vw    = (const float*)d_in[14];
    const float* fcW   = (const float*)d_in[15];
    const float* fcb   = (const float*)d_in[16];
    const float* h0    = (const float*)d_in[17];
    const float* c0    = (const float*)d_in[18];

    char* ws = (char*)d_ws;
    size_t off = 0;
    auto take = [&](size_t bytes) { char* p = ws + off; off += (bytes + 255) & ~(size_t)255; return p; };
    int*            ctrl    = (int*)           take(4096);
    unsigned short* wih0b   = (unsigned short*)take(2097152);
    unsigned short* whh0b   = (unsigned short*)take(2097152);
    unsigned short* wih1b   = (unsigned short*)take(2097152);
    unsigned short* whh1b   = (unsigned short*)take(2097152);
    unsigned short* whb     = (unsigned short*)take(524288);
    unsigned short* web     = (unsigned short*)take(524288);
    unsigned short* encb    = (unsigned short*)take(2097152);
    unsigned short* enctb   = (unsigned short*)take(2097152);
    unsigned short* xsb     = (unsigned short*)take(2097152);
    unsigned short* h0buf   = (unsigned short*)take(32768);
    unsigned short* h1buf   = (unsigned short*)take(32768);
    unsigned short* A0b     = (unsigned short*)take(8388608);
    unsigned short* hallb   = (unsigned short*)take(2097152);
    unsigned short* gmat    = (unsigned short*)take(4194304);
    float*          ph      = (float*)         take(4194304);
    float*          pe      = (float*)         take(4194304);
    float*          logitsb = (float*)         take(1048576);
    unsigned short* attb    = (unsigned short*)take(524288);
    float2*         parts   = (float2*)        take(4096000);
    float*          tgt     = (float*)         take(8192);
    unsigned short* fcWb    = (unsigned short*)take(65536000);
    size_t need = off;
    (void)in_sizes; (void)n_in;

    if (ws_size < need) {
        // Not enough scratch: fail visibly (absmax error) instead of faulting.
        hipLaunchKernelGGL(zero_out_kernel, dim3((out_size + 63) / 64), dim3(64),
                           0, stream, (float*)d_out, out_size);
        return;
    }

    hipLaunchKernelGGL(prep_kernel, dim3(62784), dim3(256), 0, stream,
                       X, enc, emb, Wih0, Whh0, Wih1, Whh1, attnW, h0, fcW,
                       wih0b, whh0b, wih1b, whh1b, whb, web, encb, enctb,
                       xsb, h0buf, h1buf, fcWb, ctrl);
    hipLaunchKernelGGL(a0_kernel, dim3(32, 32), dim3(256), 0, stream,
                       xsb, wih0b, bih0, bhh0, A0b);
    hipLaunchKernelGGL(lstm_kernel, dim3(32), dim3(512), 0, stream,
                       A0b, whh0b, wih1b, whh1b, bih1, bhh1, c0,
                       h0buf, h1buf, hallb, gmat, ctrl);
    hipLaunchKernelGGL(phpe_kernel, dim3(32, 8, 2), dim3(256), 0, stream,
                       hallb, encb, whb, web, attnb, ph, pe);
    hipLaunchKernelGGL(logits_kernel, dim3(2048), dim3(256), 0, stream,
                       ph, pe, vw, logitsb);
    hipLaunchKernelGGL(att_kernel, dim3(128), dim3(128), 0, stream,
                       logitsb, attb);
    hipLaunchKernelGGL(weighted_kernel, dim3(2, 8, 16), dim3(256), 0, stream,
                       attb, enctb, gmat);
    hipLaunchKernelGGL(fc_kernel, dim3(250, 16), dim3(256), 0, stream,
                       gmat, fcWb, fcb, parts);
    hipLaunchKernelGGL(tgt_kernel, dim3(512), dim3(256), 0, stream,
                       gmat, fcW, fcb, X, tgt);
    hipLaunchKernelGGL(finalize_kernel, dim3(1), dim3(256), 0, stream,
                       parts, tgt, X, (float*)d_out);
}